// Round 11
// baseline (178.194 us; speedup 1.0000x reference)
//
#include <hip/hip_runtime.h>
#include <hip/hip_cooperative_groups.h>

namespace cg = cooperative_groups;

// LocalAveragePoolingSegmenter — cooperative fused kernel (grid-stride, safe
// sizing, checked launch) with a 3-kernel fallback path (round-8 proven).
// B=16, T_AUDIO=4096, T_TEXT=1024, D=512.
// Output = concat( segmented_feats [B,Tt,D] f32 , text_token_len [B] as f32 ).
//
// P[b][c][j][d4] (j=0..6, fp16): local inclusive sum of frames [16c, 16c+2(j+1)).
// S [b][c][d4]   (fp16)        : chunk sums (16 frames).
// C [b][c][d4]   (c=0..256,f32): global exclusive prefix at chunk granularity.
// E[x] = C[x>>4] + (k2? P[..][k2-1] : 0) + (x&1 ? audio[x-1] : 0), k2=(x&15)>>1.

constexpr int Bv  = 16;
constexpr int TA  = 4096;
constexpr int TT  = 1024;
constexpr int Dv  = 512;
constexpr int D4  = Dv / 4;     // 128 float4 per row
constexpr int CH  = 16;         // frames per chunk
constexpr int NCk = TA / CH;    // 256 chunks per b
constexpr int NC1 = NCk + 1;
constexpr int NSL = 7;          // gran-2 partial slots per chunk
constexpr int NTHR = 256;

constexpr int AUNITS = (Bv * NCk * D4) / NTHR;  // 2048 phase-A block-units
constexpr int BUNITS = 128;                     // phase-B block-units
constexpr int CUNITS = 8192;                    // phase-C block-units (2 tokens each)

typedef float    f32x4 __attribute__((ext_vector_type(4)));
typedef _Float16 f16x4 __attribute__((ext_vector_type(4)));

__device__ __forceinline__ void f4add(float4& a, const float4& v) {
    a.x += v.x; a.y += v.y; a.z += v.z; a.w += v.w;
}
__device__ __forceinline__ void f4addh(float4& a, const f16x4& v) {
    a.x += (float)v.x; a.y += (float)v.y; a.z += (float)v.z; a.w += (float)v.w;
}
__device__ __forceinline__ f16x4 toh4(const float4& v) {
    f16x4 r = { (_Float16)v.x, (_Float16)v.y, (_Float16)v.z, (_Float16)v.w };
    return r;
}

// ---- shared phase bodies ---------------------------------------------------

__device__ __forceinline__ void phaseA_unit(
    int u, int tid, const float4* __restrict__ A,
    f16x4* __restrict__ P, f16x4* __restrict__ S)
{
    int g  = u * NTHR + tid;                   // [0, Bv*NCk*D4)
    int d4 = g & (D4 - 1);
    int c  = (g >> 7) & (NCk - 1);
    int b  = g >> 15;
    size_t abase = (size_t)(b * TA + c * CH) * D4 + d4;
    size_t pbase = ((size_t)(b * NCk + c) * NSL) * D4 + d4;
    float4 acc = {0.f, 0.f, 0.f, 0.f};
    #pragma unroll
    for (int i = 0; i < CH; ++i) {
        float4 v = A[abase + (size_t)i * D4];
        f4add(acc, v);
        if ((i & 1) && i < 15)                 // i = 1,3,...,13 -> slot (i-1)/2
            P[pbase + (size_t)((i - 1) >> 1) * D4] = toh4(acc);
    }
    S[(size_t)(b * NCk + c) * D4 + d4] = toh4(acc);
}

__device__ __forceinline__ void phaseC_unit(
    int v, int tid, const float4* __restrict__ A, const f16x4* __restrict__ P,
    const float4* __restrict__ C, const int* __restrict__ tlen,
    const int* __restrict__ align, float4* __restrict__ out)
{
    int xcd  = v & 7;                      // == blockIdx&7 when gridDim%8==0
    int w    = v >> 3;                     // [0, 1024)
    int half = tid >> 7;
    int d4   = tid & 127;
    int slot = w * 2 + half;               // [0, 2048)
    int b  = xcd + 8 * (slot >> 10);       // batches {xcd, xcd+8}
    int t  = slot & (TT - 1);
    int bt = b * TT + t;
    size_t ob = (size_t)bt * D4 + d4;

    if (t >= tlen[b]) {
        f32x4 z = {0.f, 0.f, 0.f, 0.f};
        __builtin_nontemporal_store(z, (f32x4*)&out[ob]);
        return;
    }
    int s = align[2 * bt];
    int e = align[2 * bt + 1];             // 0 <= s <= e <= TA-1

    const float4* Ab = A + (size_t)b * TA * D4;
    const float4* Cb = C + (size_t)b * NC1 * D4;
    const f16x4*  Pb = P + (size_t)b * NCk * NSL * D4;

    auto Eval = [&](int x) -> float4 {     // sum of frames < x, x in [0, TA]
        int c  = x >> 4;
        int k2 = (x & 15) >> 1;
        float4 vv = Cb[(size_t)c * D4 + d4];
        if (k2) f4addh(vv, Pb[((size_t)c * NSL + (k2 - 1)) * D4 + d4]);
        if (x & 1) f4add(vv, Ab[(size_t)(x - 1) * D4 + d4]);
        return vv;
    };

    float4 hi = Eval(e + 1);
    float4 lo = Eval(s);
    float inv = 1.f / (float)(e - s + 1);
    f32x4 r = { (hi.x - lo.x) * inv, (hi.y - lo.y) * inv,
                (hi.z - lo.z) * inv, (hi.w - lo.w) * inv };
    __builtin_nontemporal_store(r, (f32x4*)&out[ob]);
}

// ---- fused cooperative kernel ----------------------------------------------

__global__ __launch_bounds__(NTHR, 2) void k_fused(
    const float4* __restrict__ A, f16x4* __restrict__ P, f16x4* __restrict__ S,
    float4* __restrict__ C, const int* __restrict__ tlen,
    const int* __restrict__ align, float4* __restrict__ out,
    float* __restrict__ outt)
{
    cg::grid_group grid = cg::this_grid();
    int tid = threadIdx.x;
    __shared__ float4 lds[16][16];

    for (int u = blockIdx.x; u < AUNITS; u += gridDim.x)
        phaseA_unit(u, tid, A, P, S);

    grid.sync();

    for (int u = blockIdx.x; u < BUNITS; u += gridDim.x) {
        int j  = tid & 15;
        int g  = tid >> 4;                 // 0..15
        int b  = u >> 3;
        int d4 = (u & 7) * 16 + j;

        float4 run = {0.f, 0.f, 0.f, 0.f};
        float4 excl[16];
        #pragma unroll
        for (int i = 0; i < 16; ++i) {
            excl[i] = run;
            f4addh(run, S[(size_t)(b * NCk + g * 16 + i) * D4 + d4]);
        }
        lds[g][j] = run;                   // group total
        __syncthreads();
        float4 go = {0.f, 0.f, 0.f, 0.f};  // exclusive offset over groups
        for (int gp = 0; gp < g; ++gp)
            f4add(go, lds[gp][j]);

        size_t cb = (size_t)b * NC1 * D4 + d4;
        #pragma unroll
        for (int i = 0; i < 16; ++i) {
            float4 cex = go;
            f4add(cex, excl[i]);
            C[cb + (size_t)(g * 16 + i) * D4] = cex;
        }
        if (g == 15) {
            float4 tot = go;
            f4add(tot, run);
            C[cb + (size_t)NCk * D4] = tot;
        }
        if (u == 0 && tid < Bv)
            outt[tid] = (float)tlen[tid];
        __syncthreads();                   // lds reuse safety
    }

    grid.sync();

    for (int v = blockIdx.x; v < CUNITS; v += gridDim.x)
        phaseC_unit(v, tid, A, P, C, tlen, align, out);
}

// ---- fallback 3-kernel path (round-8 proven) --------------------------------

__global__ __launch_bounds__(256) void k_partials(
    const float4* __restrict__ A, f16x4* __restrict__ P, f16x4* __restrict__ S)
{
    phaseA_unit(blockIdx.x, threadIdx.x, A, P, S);
}

__global__ __launch_bounds__(64) void k_scan(
    const f16x4* __restrict__ S, float4* __restrict__ C,
    const int* __restrict__ tlen, float* __restrict__ outt)
{
    __shared__ float4 lds[16][4];
    int tid = threadIdx.x;
    int col = tid & 3;
    int g   = tid >> 2;                    // 0..15
    int b   = blockIdx.x >> 5;             // 32 blocks per b
    int d4  = (blockIdx.x & 31) * 4 + col;

    float4 run = {0.f, 0.f, 0.f, 0.f};
    float4 excl[16];
    #pragma unroll
    for (int i = 0; i < 16; ++i) {
        excl[i] = run;
        f4addh(run, S[(size_t)(b * NCk + g * 16 + i) * D4 + d4]);
    }
    lds[g][col] = run;
    __syncthreads();
    float4 go = {0.f, 0.f, 0.f, 0.f};
    for (int gp = 0; gp < g; ++gp)
        f4add(go, lds[gp][col]);

    size_t cb = (size_t)b * NC1 * D4 + d4;
    #pragma unroll
    for (int i = 0; i < 16; ++i) {
        float4 cex = go;
        f4add(cex, excl[i]);
        C[cb + (size_t)(g * 16 + i) * D4] = cex;
    }
    if (g == 15) {
        float4 tot = go;
        f4add(tot, run);
        C[cb + (size_t)NCk * D4] = tot;
    }
    if (blockIdx.x == 0 && tid < Bv)
        outt[tid] = (float)tlen[tid];
}

__global__ __launch_bounds__(256) void k_tokens(
    const float4* __restrict__ A, const f16x4* __restrict__ P,
    const float4* __restrict__ C, const int* __restrict__ tlen,
    const int* __restrict__ align, float4* __restrict__ out)
{
    phaseC_unit(blockIdx.x, threadIdx.x, A, P, C, tlen, align, out);
}

extern "C" void kernel_launch(void* const* d_in, const int* in_sizes, int n_in,
                              void* d_out, int out_size, void* d_ws, size_t ws_size,
                              hipStream_t stream)
{
    const float4* audio = (const float4*)d_in[0];      // [B,TA,D] f32
    const int*    tlen  = (const int*)d_in[4];         // [B] i32
    const int*    align = (const int*)d_in[5];         // [B,TT,2] i32
    float4* out  = (float4*)d_out;
    float*  outt = (float*)d_out + (size_t)Bv * TT * Dv;

    // ws layout: P fp16 [Bv*NCk*NSL*D4], S fp16 [Bv*NCk*D4], C fp32 [Bv*NC1*D4]
    f16x4*  P = (f16x4*)d_ws;
    f16x4*  S = P + (size_t)Bv * NCk * NSL * D4;
    float4* C = (float4*)(S + (size_t)Bv * NCk * D4);

    // --- try cooperative fused launch (host-only queries; capture-safe) -----
    bool launched = false;
    int dev = 0;
    if (hipGetDevice(&dev) == hipSuccess) {
        int coop = 0, cus = 0, perCU = 0;
        (void)hipDeviceGetAttribute(&coop, hipDeviceAttributeCooperativeLaunch, dev);
        (void)hipDeviceGetAttribute(&cus, hipDeviceAttributeMultiprocessorCount, dev);
        if (coop && cus > 0 &&
            hipOccupancyMaxActiveBlocksPerMultiprocessor(
                &perCU, (const void*)k_fused, NTHR, 0) == hipSuccess &&
            perCU > 0) {
            long cap = (long)perCU * cus;
            int nblk = (int)(cap > 1024 ? 1024 : cap);
            nblk &= ~7;                          // multiple of 8: XCD mapping
            if (nblk >= 128) {
                void* args[] = { (void*)&audio, (void*)&P, (void*)&S, (void*)&C,
                                 (void*)&tlen, (void*)&align, (void*)&out,
                                 (void*)&outt };
                launched = (hipLaunchCooperativeKernel(
                                (const void*)k_fused, dim3(nblk), dim3(NTHR),
                                args, 0, stream) == hipSuccess);
            }
        }
    }

    if (!launched) {
        k_partials<<<AUNITS, NTHR, 0, stream>>>(audio, P, S);
        k_scan<<<Bv * 32, 64, 0, stream>>>(S, C, tlen, outt);
        k_tokens<<<CUNITS, NTHR, 0, stream>>>(audio, P, C, tlen, align, out);
    }
}

// Round 12
// 44.946 us; speedup vs baseline: 3.9646x; 3.9646x over previous
//
#include <hip/hip_runtime.h>

// LocalAveragePoolingSegmenter — ROUND-5 PROVEN BEST (44.87 µs), reverted after
// cooperative-fusion experiment showed grid.sync() costs ~100µs/barrier on
// MI355X (8 non-coherent XCD L2s) vs ~3µs of launch gaps it could save.
//
// Structure: gran-2 fp16 local partials + fp32 chunk scan + XCD-affine token
// kernel with NT output stores.
// B=16, T_AUDIO=4096, T_TEXT=1024, D=512.
// Output = concat( segmented_feats [B,Tt,D] f32 , text_token_len [B] as f32 ).
//
// P[b][c][j][d4] (j=0..6, fp16): local inclusive sum of frames [16c, 16c+2(j+1)).
// S [b][c][d4]   (fp32)        : chunk sums (16 frames).
// C [b][c][d4]   (c=0..256)    : global exclusive prefix at chunk granularity.
// E[x] = C[x>>4] + (k2? P[..][k2-1] : 0) + (x&1 ? audio[x-1] : 0),  k2=(x&15)>>1.

constexpr int Bv  = 16;
constexpr int TA  = 4096;
constexpr int TT  = 1024;
constexpr int Dv  = 512;
constexpr int D4  = Dv / 4;     // 128 float4 per row
constexpr int CH  = 16;         // frames per chunk
constexpr int NCk = TA / CH;    // 256 chunks per b
constexpr int NC1 = NCk + 1;
constexpr int NSL = 7;          // gran-2 partial slots per chunk

typedef float    f32x4 __attribute__((ext_vector_type(4)));
typedef _Float16 f16x4 __attribute__((ext_vector_type(4)));

__device__ __forceinline__ void f4add(float4& a, const float4& v) {
    a.x += v.x; a.y += v.y; a.z += v.z; a.w += v.w;
}
__device__ __forceinline__ void f4addh(float4& a, const f16x4& v) {
    a.x += (float)v.x; a.y += (float)v.y; a.z += (float)v.z; a.w += (float)v.w;
}
__device__ __forceinline__ f16x4 toh4(const float4& v) {
    f16x4 r = { (_Float16)v.x, (_Float16)v.y, (_Float16)v.z, (_Float16)v.w };
    return r;
}

// K1: per (b, chunk, d4): fp16 gran-2 partials (7 slots) -> P, fp32 chunk total -> S.
__global__ __launch_bounds__(256) void k_partials(
    const float4* __restrict__ A, f16x4* __restrict__ P, float4* __restrict__ S)
{
    int g  = blockIdx.x * 256 + threadIdx.x;   // [0, Bv*NCk*D4)
    int d4 = g & (D4 - 1);
    int c  = (g >> 7) & (NCk - 1);
    int b  = g >> 15;
    size_t abase = (size_t)(b * TA + c * CH) * D4 + d4;
    size_t pbase = ((size_t)(b * NCk + c) * NSL) * D4 + d4;
    float4 acc = {0.f, 0.f, 0.f, 0.f};
    #pragma unroll
    for (int i = 0; i < CH; ++i) {
        float4 v = A[abase + (size_t)i * D4];
        f4add(acc, v);
        if ((i & 1) && i < 15)                 // i = 1,3,...,13 -> slot (i-1)/2
            P[pbase + (size_t)((i - 1) >> 1) * D4] = toh4(acc);
    }
    S[(size_t)(b * NCk + c) * D4 + d4] = acc;
}

// K2: chunk-level exclusive scan S -> C (fp32), + tail lens output fused in.
// Block = 256 threads = 16 groups (g) x 16 cols (j); 8 blocks per b.
__global__ __launch_bounds__(256) void k_scan(
    const float4* __restrict__ S, float4* __restrict__ C,
    const int* __restrict__ tlen, float* __restrict__ outt)
{
    __shared__ float4 lds[16][16];
    int tid = threadIdx.x;
    int j  = tid & 15;
    int g  = tid >> 4;
    int b  = blockIdx.x >> 3;
    int d4 = (blockIdx.x & 7) * 16 + j;

    float4 run = {0.f, 0.f, 0.f, 0.f};
    float4 excl[16];
    #pragma unroll
    for (int i = 0; i < 16; ++i) {
        excl[i] = run;
        float4 s = S[(size_t)(b * NCk + g * 16 + i) * D4 + d4];
        f4add(run, s);
    }
    lds[g][j] = run;                       // group total
    __syncthreads();
    float4 go = {0.f, 0.f, 0.f, 0.f};      // exclusive offset over groups
    for (int gp = 0; gp < g; ++gp)
        f4add(go, lds[gp][j]);

    size_t cb = (size_t)b * NC1 * D4 + d4;
    #pragma unroll
    for (int i = 0; i < 16; ++i) {
        float4 cex = go;
        f4add(cex, excl[i]);
        C[cb + (size_t)(g * 16 + i) * D4] = cex;
    }
    if (g == 15) {
        float4 tot = go;
        f4add(tot, run);
        C[cb + (size_t)NCk * D4] = tot;    // C[b][256] = grand total
    }
    if (blockIdx.x == 0 && tid < Bv)
        outt[tid] = (float)tlen[tid];
}

// K3: per-token mean. XCD-affine: batch b pinned to XCD b&7 (C/P L2-resident).
__global__ __launch_bounds__(128) void k_tokens(
    const float4* __restrict__ A, const f16x4* __restrict__ P,
    const float4* __restrict__ C, const int* __restrict__ tlen,
    const int* __restrict__ align, float4* __restrict__ out)
{
    int xcd  = blockIdx.x & 7;
    int slot = blockIdx.x >> 3;            // [0, 2048)
    int b  = xcd + 8 * (slot >> 10);       // batches {xcd, xcd+8}
    int t  = slot & (TT - 1);
    int bt = b * TT + t;
    int d4 = threadIdx.x;
    size_t ob = (size_t)bt * D4 + d4;

    if (t >= tlen[b]) {
        f32x4 z = {0.f, 0.f, 0.f, 0.f};
        __builtin_nontemporal_store(z, (f32x4*)&out[ob]);
        return;
    }
    int s = align[2 * bt];
    int e = align[2 * bt + 1];             // 0 <= s <= e <= TA-1

    const float4* Ab = A + (size_t)b * TA * D4;
    const float4* Cb = C + (size_t)b * NC1 * D4;
    const f16x4*  Pb = P + (size_t)b * NCk * NSL * D4;

    auto Eval = [&](int x) -> float4 {     // sum of frames < x, x in [0, TA]
        int c  = x >> 4;
        int k2 = (x & 15) >> 1;
        float4 v = Cb[(size_t)c * D4 + d4];
        if (k2) f4addh(v, Pb[((size_t)c * NSL + (k2 - 1)) * D4 + d4]);
        if (x & 1) f4add(v, Ab[(size_t)(x - 1) * D4 + d4]);
        return v;
    };

    float4 hi = Eval(e + 1);
    float4 lo = Eval(s);
    float inv = 1.f / (float)(e - s + 1);
    f32x4 r = { (hi.x - lo.x) * inv, (hi.y - lo.y) * inv,
                (hi.z - lo.z) * inv, (hi.w - lo.w) * inv };
    __builtin_nontemporal_store(r, (f32x4*)&out[ob]);
}

extern "C" void kernel_launch(void* const* d_in, const int* in_sizes, int n_in,
                              void* d_out, int out_size, void* d_ws, size_t ws_size,
                              hipStream_t stream)
{
    const float* audio = (const float*)d_in[0];        // [B,TA,D] f32
    const int*   tlen  = (const int*)d_in[4];          // [B] i32
    const int*   align = (const int*)d_in[5];          // [B,TT,2] i32
    float* out = (float*)d_out;

    // ws layout: P fp16 [Bv*NCk*NSL*D4] (29.4 MB), then S, C fp32.
    f16x4*  P = (f16x4*)d_ws;
    float4* S = (float4*)((char*)d_ws + (size_t)Bv * NCk * NSL * D4 * sizeof(f16x4));
    float4* C = S + (size_t)Bv * NCk * D4;

    k_partials<<<(Bv * NCk * D4) / 256, 256, 0, stream>>>(
        (const float4*)audio, P, S);
    k_scan<<<(Bv * D4) / 16, 256, 0, stream>>>(
        S, C, tlen, out + (size_t)Bv * TT * Dv);
    k_tokens<<<Bv * TT, 128, 0, stream>>>(
        (const float4*)audio, P, C, tlen, align, (float4*)out);
}